// Round 1
// baseline (249.540 us; speedup 1.0000x reference)
//
#include <hip/hip_runtime.h>
#include <hip/hip_bf16.h>

#define G_ 64
#define N_ 1024
#define DIN 128
#define DH 256
#define DOUT 10

// ---------------------------------------------------------------------------
// Kernel 1: per-node inverse norm + per-graph u = sum_n xn[n]  (one x pass)
// Block = 256 threads (4 waves), 256 nodes/block, 4 blocks/graph.
// Wave-per-node: lane L reads x[m][2L:2L+2] (coalesced), butterfly-reduce
// sum-of-squares across 64 lanes, accumulate xn into per-lane registers.
// ---------------------------------------------------------------------------
__global__ __launch_bounds__(256) void k1_norm_u(
    const float* __restrict__ x, float* __restrict__ norminv, float* __restrict__ u) {
  const int g = blockIdx.x >> 2;
  const int base = blockIdx.x << 8;          // first node of this block
  const int wave = threadIdx.x >> 6;
  const int lane = threadIdx.x & 63;
  __shared__ float red[4][DIN];
  float a0 = 0.f, a1 = 0.f;
  const int mbase = base + wave * 64;
  for (int i = 0; i < 64; ++i) {
    const int m = mbase + i;
    const float2 v = ((const float2*)(x + (size_t)m * DIN))[lane];
    float ss = v.x * v.x + v.y * v.y;
    #pragma unroll
    for (int off = 32; off; off >>= 1) ss += __shfl_xor(ss, off, 64);
    const float ninv = rsqrtf(ss + 1e-24f);
    if (lane == 0) norminv[m] = ninv;
    a0 += v.x * ninv;
    a1 += v.y * ninv;
  }
  red[wave][2 * lane] = a0;
  red[wave][2 * lane + 1] = a1;
  __syncthreads();
  if (threadIdx.x < DIN) {
    const float t = red[0][threadIdx.x] + red[1][threadIdx.x] +
                    red[2][threadIdx.x] + red[3][threadIdx.x];
    atomicAdd(&u[g * DIN + threadIdx.x], t);   // 4 adds per (g,d)
  }
}

// ---------------------------------------------------------------------------
// Kernel 2: hw[g][d] += sum_m s[m] * relu(x[m] @ W1 + b1)[d]
// Grid = 64 graphs * 16 tiles; block = 256 threads = 4 waves, 64 nodes/block.
// Each wave owns 16 nodes x all 256 d: acc[16] float4 (d = lane*4..+3).
// x enters as wave-uniform SCALAR loads (SGPR operand of v_fma -> no LDS/VMEM
// vector cost); W1 staged in LDS in K=16 chunks, one ds_read_b128/k/lane
// (bank pattern 4*lane -> 2-way, free). 64 FMA per k per wave => VALU-bound.
// ---------------------------------------------------------------------------
__global__ __launch_bounds__(256) void k2_gemm_ws(
    const float* __restrict__ x, const float* __restrict__ W1,
    const float* __restrict__ b1, const float* __restrict__ norminv,
    const float* __restrict__ u, float* __restrict__ hw) {
  constexpr int KC = 16;
  __shared__ float ws[KC][DH];     // 16 KB W1 chunk
  __shared__ float red[4][DH];     // 4 KB cross-wave reduce
  const int g = blockIdx.x >> 4;
  const int tile = blockIdx.x & 15;
  const int lane = threadIdx.x & 63;
  const int wave = __builtin_amdgcn_readfirstlane(threadIdx.x >> 6);
  const int gnode0 = (g << 10) + (tile << 6) + (wave << 4);
  const float* xbase = x + (size_t)gnode0 * DIN;

  // s[m] = (u . x[m]) * norminv[m] - 1 for this wave's 16 nodes (kept in SGPRs)
  const float2 u2 = *(const float2*)(u + g * DIN + 2 * lane);
  float s_arr[16];
  #pragma unroll
  for (int m = 0; m < 16; ++m) {
    const float2 v = *(const float2*)(xbase + (size_t)m * DIN + 2 * lane);
    float p = v.x * u2.x + v.y * u2.y;
    #pragma unroll
    for (int off = 32; off; off >>= 1) p += __shfl_xor(p, off, 64);
    const float ninv = norminv[gnode0 + m];                 // uniform -> s_load
    s_arr[m] = __builtin_amdgcn_readfirstlane(p) * ninv - 1.0f;
  }

  float4 acc[16];
  #pragma unroll
  for (int m = 0; m < 16; ++m) acc[m] = make_float4(0.f, 0.f, 0.f, 0.f);

  for (int kc = 0; kc < DIN / KC; ++kc) {
    // stage 16x256 W1 chunk (contiguous rows), coalesced float4
    #pragma unroll
    for (int it = 0; it < 4; ++it) {
      const int idx = it * 256 + threadIdx.x;
      ((float4*)ws)[idx] = ((const float4*)(W1 + kc * KC * DH))[idx];
    }
    __syncthreads();
    #pragma unroll
    for (int k4 = 0; k4 < KC / 4; ++k4) {
      // 16 wave-uniform float4 x loads -> s_load_dwordx4 (scalar cache)
      float4 xv[16];
      #pragma unroll
      for (int m = 0; m < 16; ++m)
        xv[m] = *(const float4*)(xbase + (size_t)m * DIN + kc * KC + k4 * 4);
      #pragma unroll
      for (int kk = 0; kk < 4; ++kk) {
        const float4 w = *(const float4*)&ws[k4 * 4 + kk][lane * 4];
        #pragma unroll
        for (int m = 0; m < 16; ++m) {
          const float xs = (kk == 0) ? xv[m].x : (kk == 1) ? xv[m].y
                         : (kk == 2) ? xv[m].z : xv[m].w;
          acc[m].x = fmaf(xs, w.x, acc[m].x);
          acc[m].y = fmaf(xs, w.y, acc[m].y);
          acc[m].z = fmaf(xs, w.z, acc[m].z);
          acc[m].w = fmaf(xs, w.w, acc[m].w);
        }
      }
    }
    __syncthreads();
  }

  // epilogue: bias + relu + s-weighted reduction over this wave's 16 nodes
  const float4 bb = *(const float4*)(b1 + lane * 4);
  float4 part = make_float4(0.f, 0.f, 0.f, 0.f);
  #pragma unroll
  for (int m = 0; m < 16; ++m) {
    part.x += s_arr[m] * fmaxf(acc[m].x + bb.x, 0.f);
    part.y += s_arr[m] * fmaxf(acc[m].y + bb.y, 0.f);
    part.z += s_arr[m] * fmaxf(acc[m].z + bb.z, 0.f);
    part.w += s_arr[m] * fmaxf(acc[m].w + bb.w, 0.f);
  }
  *(float4*)&red[wave][lane * 4] = part;
  __syncthreads();
  {
    const int d = threadIdx.x;   // 256 threads = 256 d
    const float tot = red[0][d] + red[1][d] + red[2][d] + red[3][d];
    atomicAdd(&hw[g * DH + d], tot);   // 16 adds per (g,d)
  }
}

// ---------------------------------------------------------------------------
// Kernel 3: pooled = hw/N @ W2 + b2 ; log_softmax. One 64-thread block/graph.
// ---------------------------------------------------------------------------
__global__ __launch_bounds__(64) void k3_head(
    const float* __restrict__ hw, const float* __restrict__ W2,
    const float* __restrict__ b2, float* __restrict__ out) {
  const int g = blockIdx.x;
  const int t = threadIdx.x;
  __shared__ float partial[40];
  __shared__ float p[DOUT];
  if (t < 40) {
    const int c = t % 10, q = t / 10;
    const float* hg = hw + g * DH + q * 64;
    float a = 0.f;
    #pragma unroll
    for (int k = 0; k < 64; ++k) a = fmaf(hg[k], W2[(q * 64 + k) * DOUT + c], a);
    partial[t] = a;
  }
  __syncthreads();
  if (t < DOUT) {
    p[t] = (partial[t] + partial[t + 10] + partial[t + 20] + partial[t + 30]) *
               (1.0f / N_) + b2[t];
  }
  __syncthreads();
  if (t < DOUT) {
    float mx = p[0];
    #pragma unroll
    for (int c = 1; c < DOUT; ++c) mx = fmaxf(mx, p[c]);
    float se = 0.f;
    #pragma unroll
    for (int c = 0; c < DOUT; ++c) se += expf(p[c] - mx);
    out[g * DOUT + t] = p[t] - (mx + logf(se));
  }
}

extern "C" void kernel_launch(void* const* d_in, const int* in_sizes, int n_in,
                              void* d_out, int out_size, void* d_ws, size_t ws_size,
                              hipStream_t stream) {
  const float* x  = (const float*)d_in[0];
  // d_in[1] = batch (sorted, equal-sized graphs) -> unused
  const float* W1 = (const float*)d_in[2];
  const float* b1 = (const float*)d_in[3];
  const float* W2 = (const float*)d_in[4];
  const float* b2 = (const float*)d_in[5];
  float* out = (float*)d_out;

  // workspace: [hw 64*256][u 64*128][norminv 65536] floats
  float* hw = (float*)d_ws;
  float* u  = hw + G_ * DH;
  float* norminv = u + G_ * DIN;

  hipMemsetAsync(d_ws, 0, (size_t)(G_ * DH + G_ * DIN) * sizeof(float), stream);
  k1_norm_u<<<G_ * 4, 256, 0, stream>>>(x, norminv, u);
  k2_gemm_ws<<<G_ * 16, 256, 0, stream>>>(x, W1, b1, norminv, u, hw);
  k3_head<<<G_, 64, 0, stream>>>(hw, W2, b2, out);
}

// Round 2
// 111.699 us; speedup vs baseline: 2.2341x; 2.2341x over previous
//
#include <hip/hip_runtime.h>
#include <hip/hip_bf16.h>
#include <string.h>

#define G_ 64
#define N_ 1024
#define DIN 128
#define DH 256
#define DOUT 10

typedef float floatx4 __attribute__((ext_vector_type(4)));
typedef short shortx8 __attribute__((ext_vector_type(8)));

__device__ __forceinline__ ushort f2bf(float f) {
  unsigned u = __builtin_bit_cast(unsigned, f);
  unsigned r = (u + 0x7FFFu + ((u >> 16) & 1u)) >> 16;   // RNE
  return (ushort)r;
}
__device__ __forceinline__ float bflo(unsigned q) {
  return __builtin_bit_cast(float, q << 16);
}
__device__ __forceinline__ float bfhi(unsigned q) {
  return __builtin_bit_cast(float, q & 0xFFFF0000u);
}

// ---------------------------------------------------------------------------
// k0: W1 [128][256] fp32  ->  W1t [256][128] bf16 (B^T layout for B-frags)
// ---------------------------------------------------------------------------
__global__ __launch_bounds__(256) void k0_w1t(
    const float* __restrict__ W1, ushort* __restrict__ w1t) {
  const int idx = blockIdx.x * 256 + threadIdx.x;   // 128*256 = 32768 elems
  const int k = idx >> 8, d = idx & 255;
  w1t[d * DIN + k] = f2bf(W1[k * DH + d]);          // coalesced read
}

// ---------------------------------------------------------------------------
// k1: per-node inverse norm + per-graph u = sum xn  +  x -> bf16 (xb).
// 1024 blocks (4/CU), 64 nodes/block, wave-per-node (lane = d-pair).
// ---------------------------------------------------------------------------
__global__ __launch_bounds__(256) void k1_norm_u(
    const float* __restrict__ x, float* __restrict__ norminv,
    float* __restrict__ u, ushort* __restrict__ xb) {
  const int g = blockIdx.x >> 4;
  const int wave = threadIdx.x >> 6;
  const int lane = threadIdx.x & 63;
  __shared__ float red[4][DIN];
  float a0 = 0.f, a1 = 0.f;
  const int mbase = blockIdx.x * 64 + wave * 16;
  for (int i = 0; i < 16; ++i) {
    const int m = mbase + i;
    const float2 v = ((const float2*)(x + (size_t)m * DIN))[lane];
    float ss = v.x * v.x + v.y * v.y;
    #pragma unroll
    for (int off = 32; off; off >>= 1) ss += __shfl_xor(ss, off, 64);
    const float ninv = rsqrtf(ss + 1e-24f);
    if (lane == 0) norminv[m] = ninv;
    ((unsigned*)xb)[(size_t)m * (DIN / 2) + lane] =
        (unsigned)f2bf(v.x) | ((unsigned)f2bf(v.y) << 16);
    a0 = fmaf(v.x, ninv, a0);
    a1 = fmaf(v.y, ninv, a1);
  }
  red[wave][2 * lane] = a0;
  red[wave][2 * lane + 1] = a1;
  __syncthreads();
  if (threadIdx.x < DIN) {
    const float t = red[0][threadIdx.x] + red[1][threadIdx.x] +
                    red[2][threadIdx.x] + red[3][threadIdx.x];
    atomicAdd(&u[g * DIN + threadIdx.x], t);   // 16 adds per (g,d)
  }
}

// ---------------------------------------------------------------------------
// k2: hw[g][d] = sum_m s[m] * relu(x[m] @ W1 + b1)[d]  via bf16 MFMA.
// Grid = 64 g * 8 tiles (128 nodes); block = 4 waves, wave owns 64 d.
// B-frags (W1t slice) hoisted in regs (16 x short8). Per m-tile: 4 A-frag
// loads + 16 MFMA (16x16x32), then fused bias+relu+s-weight reduce.
// No LDS staging: A/B frag loads are 16B/lane contiguous from L1/L2.
// ---------------------------------------------------------------------------
__global__ __launch_bounds__(256) void k2_mfma(
    const ushort* __restrict__ xb, const ushort* __restrict__ w1t,
    const float* __restrict__ b1, const float* __restrict__ norminv,
    const float* __restrict__ u, float* __restrict__ hw) {
  const int g = blockIdx.x >> 3;
  const int mb = (blockIdx.x & 7) << 7;        // first node (in-graph) of block
  const int lane = threadIdx.x & 63;
  const int wave = threadIdx.x >> 6;
  const int quad = lane >> 4;
  const int l16 = lane & 15;
  __shared__ float u_lds[DIN];
  __shared__ float s_lds[128];

  if (threadIdx.x < DIN) u_lds[threadIdx.x] = u[g * DIN + threadIdx.x];
  __syncthreads();

  // s[m] = ninv[m]*(u . x[m]) - 1 for the block's 128 nodes (2 threads/node)
  {
    const int nd = threadIdx.x >> 1;
    const int half = threadIdx.x & 1;
    const size_t m = (size_t)(g << 10) + mb + nd;
    const uint4* xr = (const uint4*)(xb + m * DIN + half * 64);
    float p = 0.f;
    #pragma unroll
    for (int j = 0; j < 8; ++j) {
      const uint4 q = xr[j];
      const float* ub = &u_lds[half * 64 + j * 8];
      p = fmaf(bflo(q.x), ub[0], p); p = fmaf(bfhi(q.x), ub[1], p);
      p = fmaf(bflo(q.y), ub[2], p); p = fmaf(bfhi(q.y), ub[3], p);
      p = fmaf(bflo(q.z), ub[4], p); p = fmaf(bfhi(q.z), ub[5], p);
      p = fmaf(bflo(q.w), ub[6], p); p = fmaf(bfhi(q.w), ub[7], p);
    }
    p += __shfl_xor(p, 1, 64);
    if (!half) s_lds[nd] = p * norminv[m] - 1.0f;
  }
  __syncthreads();

  // Hoist B fragments: wave's 64-d slice of W1t. B[k][n]: n=l16, k=quad*8+j.
  shortx8 bfr[4][4];   // [dt][kt]
  #pragma unroll
  for (int dt = 0; dt < 4; ++dt) {
    const int d = (wave << 6) + (dt << 4) + l16;
    #pragma unroll
    for (int kt = 0; kt < 4; ++kt)
      bfr[dt][kt] = *(const shortx8*)(w1t + (size_t)d * DIN + (kt << 5) + (quad << 3));
  }
  float b1v[4];
  #pragma unroll
  for (int dt = 0; dt < 4; ++dt) b1v[dt] = b1[(wave << 6) + (dt << 4) + l16];

  float wsum[4] = {0.f, 0.f, 0.f, 0.f};
  for (int mt = 0; mt < 8; ++mt) {
    // A frags: A[m][k]: m=l16, k=quad*8+j, contiguous 16B per lane
    const ushort* ar = xb + ((size_t)(g << 10) + mb + (mt << 4) + l16) * DIN;
    shortx8 af[4];
    #pragma unroll
    for (int kt = 0; kt < 4; ++kt)
      af[kt] = *(const shortx8*)(ar + (kt << 5) + (quad << 3));

    floatx4 acc[4] = {{0.f, 0.f, 0.f, 0.f}, {0.f, 0.f, 0.f, 0.f},
                      {0.f, 0.f, 0.f, 0.f}, {0.f, 0.f, 0.f, 0.f}};
    #pragma unroll
    for (int kt = 0; kt < 4; ++kt)
      #pragma unroll
      for (int dt = 0; dt < 4; ++dt)
        acc[dt] = __builtin_amdgcn_mfma_f32_16x16x32_bf16(af[kt], bfr[dt][kt],
                                                          acc[dt], 0, 0, 0);
    // epilogue: bias + relu + s-weight; C layout row=quad*4+r, col=l16
    #pragma unroll
    for (int dt = 0; dt < 4; ++dt) {
      float bs = 0.f;
      #pragma unroll
      for (int r = 0; r < 4; ++r) {
        const float h = fmaxf(acc[dt][r] + b1v[dt], 0.f);
        bs = fmaf(s_lds[(mt << 4) + (quad << 2) + r], h, bs);
      }
      wsum[dt] += bs;
    }
  }
  #pragma unroll
  for (int dt = 0; dt < 4; ++dt) {
    float w = wsum[dt];
    w += __shfl_xor(w, 16, 64);
    w += __shfl_xor(w, 32, 64);
    if (quad == 0)
      atomicAdd(&hw[g * DH + (wave << 6) + (dt << 4) + l16], w);  // 8 adds/(g,d)
  }
}

// ---------------------------------------------------------------------------
// k3: pooled = hw/N @ W2 + b2 ; log_softmax. One 64-thread block per graph.
// ---------------------------------------------------------------------------
__global__ __launch_bounds__(64) void k3_head(
    const float* __restrict__ hw, const float* __restrict__ W2,
    const float* __restrict__ b2, float* __restrict__ out) {
  const int g = blockIdx.x;
  const int t = threadIdx.x;
  __shared__ float partial[40];
  __shared__ float p[DOUT];
  if (t < 40) {
    const int c = t % 10, q = t / 10;
    const float* hg = hw + g * DH + q * 64;
    float a = 0.f;
    #pragma unroll
    for (int k = 0; k < 64; ++k) a = fmaf(hg[k], W2[(q * 64 + k) * DOUT + c], a);
    partial[t] = a;
  }
  __syncthreads();
  if (t < DOUT) {
    p[t] = (partial[t] + partial[t + 10] + partial[t + 20] + partial[t + 30]) *
               (1.0f / N_) + b2[t];
  }
  __syncthreads();
  if (t < DOUT) {
    float mx = p[0];
    #pragma unroll
    for (int c = 1; c < DOUT; ++c) mx = fmaxf(mx, p[c]);
    float se = 0.f;
    #pragma unroll
    for (int c = 0; c < DOUT; ++c) se += expf(p[c] - mx);
    out[g * DOUT + t] = p[t] - (mx + logf(se));
  }
}

extern "C" void kernel_launch(void* const* d_in, const int* in_sizes, int n_in,
                              void* d_out, int out_size, void* d_ws, size_t ws_size,
                              hipStream_t stream) {
  const float* x  = (const float*)d_in[0];
  // d_in[1] = batch (sorted, equal-sized) -> unused
  const float* W1 = (const float*)d_in[2];
  const float* b1 = (const float*)d_in[3];
  const float* W2 = (const float*)d_in[4];
  const float* b2 = (const float*)d_in[5];
  float* out = (float*)d_out;

  // ws layout (floats): hw[64*256] u[64*128] norminv[65536]; then bf16 blobs
  float* hw = (float*)d_ws;
  float* u  = hw + G_ * DH;
  float* norminv = u + G_ * DIN;
  ushort* xb  = (ushort*)(norminv + G_ * N_);          // [65536][128] bf16
  ushort* w1t = xb + (size_t)G_ * N_ * DIN;            // [256][128] bf16

  hipMemsetAsync(d_ws, 0, (size_t)(G_ * DH + G_ * DIN) * sizeof(float), stream);
  k0_w1t<<<DIN, 256, 0, stream>>>(W1, w1t);
  k1_norm_u<<<G_ * 16, 256, 0, stream>>>(x, norminv, u, xb);
  k2_mfma<<<G_ * 8, 256, 0, stream>>>(xb, w1t, b1, norminv, u, hw);
  k3_head<<<G_, 64, 0, stream>>>(hw, W2, b2, out);
}